// Round 10
// baseline (1221.198 us; speedup 1.0000x reference)
//
#include <hip/hip_runtime.h>
#include <hip/hip_bf16.h>

typedef __attribute__((ext_vector_type(4))) float f32x4;
typedef __attribute__((ext_vector_type(8))) short short8;
typedef __attribute__((ext_vector_type(8))) __bf16 bf16x8;

union FragU { bf16x8 h; short8 s; };

typedef const __attribute__((address_space(1))) void gvoid_t;
typedef __attribute__((address_space(3))) void lvoid_t;

static __device__ __forceinline__ void gload16(const void* g, void* l) {
  __builtin_amdgcn_global_load_lds((gvoid_t*)g, (lvoid_t*)l, 16, 0, 0);
}

static __device__ __forceinline__ short8 cvt8(const f32x4 a0, const f32x4 a1) {
  bf16x8 hv;
  hv[0] = (__bf16)a0[0]; hv[1] = (__bf16)a0[1];
  hv[2] = (__bf16)a0[2]; hv[3] = (__bf16)a0[3];
  hv[4] = (__bf16)a1[0]; hv[5] = (__bf16)a1[1];
  hv[6] = (__bf16)a1[2]; hv[7] = (__bf16)a1[3];
  FragU u; u.h = hv; return u.s;
}

// ---------------------------------------------------------------------------
// Layer-0 GEMM + bf16 fragment-cache production. BK=64.
// A: reg-staged (each thread 128 B contiguous f32 -> cvt bf16 -> ds_write,
//    XOR-swizzled [row128][gran8]); B: global_load_lds (issued BEFORE A-loads
//    so the compiler's reg-dep vmcnt wait in writeA also drains B).
// 3 LDS buffers (72 KB), one barrier per 64-k tile. Cache stores from cons
// fragments (coalesced 1 KB/wave). Ordering proof:
//   iter j issues: cons(j) | writeA(j+1) [auto-wait A(j+1), drains B(j+1)
//   and older] | loadB(j+2); loadA(j+2) | lgkmcnt(0); s_barrier.
//   cons(h) needs: sA(h) [written iter h-1, barrier]; sB(h) [B(h) drained at
//   iter h-1's writeA wait, per wave, before that wave's barrier].
// ---------------------------------------------------------------------------
__global__ __launch_bounds__(256) void gemm_l0(
    const float* __restrict__ Au, const __bf16* __restrict__ BTu,
    __bf16* __restrict__ AcU, float* __restrict__ Pu,
    int Mu, int Ku, int KTu, int padKu,
    const float* __restrict__ Am, const __bf16* __restrict__ BTm,
    __bf16* __restrict__ AcM, float* __restrict__ Pm,
    int Mm, int Km, int KTm, int padKm,
    int nbU, int rbU, int rbM)
{
  __shared__ __bf16 sA[3][8192];   // 3 x 16 KB: [row(128)][gran(8)^row&7][8]
  __shared__ __bf16 sB[3][4096];   // 3 x  8 KB: [row(64)][gran(8)^row&7][8]

  const int t = threadIdx.x;
  const int w = t >> 6;
  const int lane = t & 63;
  const int r = lane & 15;
  const int g = lane >> 4;

  const float* A; const __bf16* BT; __bf16* Ac; float* P;
  int M, K, KT, Kpad, rowBlk, split;
  {
    int bx = blockIdx.x;
    if (bx < nbU) {
      A = Au; BT = BTu; Ac = AcU; P = Pu; M = Mu; K = Ku; KT = KTu; Kpad = padKu;
      rowBlk = bx % rbU; split = bx / rbU;
    } else {
      int b2 = bx - nbU;
      A = Am; BT = BTm; Ac = AcM; P = Pm; M = Mm; K = Km; KT = KTm; Kpad = padKm;
      rowBlk = b2 % rbM; split = b2 / rbM;
    }
  }
  const int rowBase = rowBlk * 128;
  const int s0 = split * 32;             // 64-k tiles
  const int ns = min(32, KT - s0);       // >= 25 by config

  f32x4 acc[2][4];
  #pragma unroll
  for (int m = 0; m < 2; ++m)
    #pragma unroll
    for (int n = 0; n < 4; ++n)
      acc[m][n] = (f32x4){0.f, 0.f, 0.f, 0.f};

  // A reg-stage mapping: thread -> (lrow = t>>1, seg = t&1), 128 B contiguous
  const int lrow = t >> 1, seg = t & 1;
  int growA = rowBase + lrow; if (growA > M - 1) growA = M - 1;
  const float* aRow = A + (size_t)growA * K;
  f32x4 ar[8];

  auto loadA = [&](int h) {
    const int kb = (s0 + h) * 64 + seg * 32;
    #pragma unroll
    for (int j = 0; j < 8; ++j) {
      int kj = kb + j * 4;
      if (kj > K - 4) kj = K - 4;        // clamp addr; zeroed at cvt
      ar[j] = *(const f32x4*)(aRow + kj);
    }
  };
  auto writeA = [&](int h) {             // consumes ar[] (auto vmcnt wait)
    const int kb = (s0 + h) * 64 + seg * 32;
    const int buf = h % 3;
    #pragma unroll
    for (int q = 0; q < 4; ++q) {
      short8 cv;
      if (kb + q * 8 < K) cv = cvt8(ar[2 * q], ar[2 * q + 1]);  // 8|K: all-in/out
      else cv = (short8){0, 0, 0, 0, 0, 0, 0, 0};
      const int qd = (seg * 4 + q) ^ (lrow & 7);
      *(short8*)&sA[buf][lrow * 64 + qd * 8] = cv;
    }
  };

  // B stage: wave w covers rows [16w,16w+16); lane -> (row=16w+(lane>>3)(+8), gran=lane&7)
  const int bq = lane & 7;
  const int br0 = w * 16 + (lane >> 3);
  const __bf16* bS0 = BT + (size_t)br0 * Kpad + (size_t)((bq ^ (br0 & 7)) * 8);
  const __bf16* bS1 = BT + (size_t)(br0 + 8) * Kpad + (size_t)((bq ^ (br0 & 7)) * 8);
  auto loadB = [&](int h) {
    const int buf = h % 3;
    const int k0 = (s0 + h) * 64;
    gload16(bS0 + k0, &sB[buf][w * 1024]);
    gload16(bS1 + k0, &sB[buf][w * 1024 + 512]);
  };

  auto cons = [&](int h) {
    const int buf = h % 3;
    __bf16* cp = Ac + (((size_t)rowBlk * KT + (s0 + h)) << 13) + (size_t)lane * 8;
    #pragma unroll
    for (int ks = 0; ks < 2; ++ks) {
      FragU aF[2], bF[4];
      const int gx = ((ks * 4 + g) ^ (r & 7)) * 8;   // (row&7)==(r&7) for all rows used
      aF[0].s = *(const short8*)&sA[buf][(w * 32 + r) * 64 + gx];
      aF[1].s = *(const short8*)&sA[buf][(w * 32 + 16 + r) * 64 + gx];
      #pragma unroll
      for (int n = 0; n < 4; ++n)
        bF[n].s = *(const short8*)&sB[buf][(n * 16 + r) * 64 + gx];
      #pragma unroll
      for (int m = 0; m < 2; ++m)
        #pragma unroll
        for (int n = 0; n < 4; ++n)
          acc[m][n] = __builtin_amdgcn_mfma_f32_16x16x32_bf16(
              aF[m].s, bF[n].s, acc[m][n], 0, 0, 0);
      *(short8*)(cp + (size_t)((ks * 8 + w * 2 + 0) * 512)) = aF[0].s;
      *(short8*)(cp + (size_t)((ks * 8 + w * 2 + 1) * 512)) = aF[1].s;
    }
  };

  // prologue
  loadB(0); loadA(0);
  writeA(0);                   // waits A(0) -> drains B(0); fills sA0
  loadB(1); loadA(1);
  asm volatile("s_waitcnt lgkmcnt(0)" ::: "memory");
  __builtin_amdgcn_s_barrier();
  asm volatile("" ::: "memory");

  for (int h = 0; h < ns; ++h) {
    cons(h);
    if (h + 1 < ns) writeA(h + 1);               // auto-wait A(h+1); drains B(h+1)
    if (h + 2 < ns) { loadB(h + 2); loadA(h + 2); }
    asm volatile("s_waitcnt lgkmcnt(0)" ::: "memory");
    __builtin_amdgcn_s_barrier();
    asm volatile("" ::: "memory");
  }

  // epilogue: C/D layout col = lane&15, row = (lane>>4)*4 + reg
  float* Pp = P + (size_t)split * M * 64;
  #pragma unroll
  for (int m = 0; m < 2; ++m) {
    #pragma unroll
    for (int j = 0; j < 4; ++j) {
      const int row = rowBase + w * 32 + m * 16 + g * 4 + j;
      if (row < M) {
        #pragma unroll
        for (int n = 0; n < 4; ++n)
          Pp[(size_t)row * 64 + n * 16 + r] = acc[m][n][j];
      }
    }
  }
}

// ---------------------------------------------------------------------------
// Layers 1-2 GEMM over the fragment-ordered bf16 cache. BK=32.
// 3 buffers (36 KB -> 4 blocks/CU); vmcnt(3) counted wait; clamped tail.
// ---------------------------------------------------------------------------
__global__ __launch_bounds__(256) void gemm_l12(
    const __bf16* __restrict__ AcU, const __bf16* __restrict__ BTu,
    float* __restrict__ Pu, int Mu, int KTu, int padKu,
    const __bf16* __restrict__ AcM, const __bf16* __restrict__ BTm,
    float* __restrict__ Pm, int Mm, int KTm, int padKm,
    int nbU, int rbU, int rbM)
{
  __shared__ __bf16 sA[3][4096];   // 3 x 8 KB  [slot(8)=w*2+m][lane(64)][8]
  __shared__ __bf16 sB[3][2048];   // 3 x 4 KB  [row(64)][gran(4)^((row>>1)&3)][8]

  const int t = threadIdx.x;
  const int w = t >> 6;
  const int lane = t & 63;
  const int r = lane & 15;
  const int g = lane >> 4;

  const __bf16 *Ac, *BT; float* P;
  int M, KT, Kpad, rowBlk, split;
  {
    int bx = blockIdx.x;
    if (bx < nbU) {
      Ac = AcU; BT = BTu; P = Pu; M = Mu; KT = KTu; Kpad = padKu;
      rowBlk = bx % rbU; split = bx / rbU;
    } else {
      int b2 = bx - nbU;
      Ac = AcM; BT = BTm; P = Pm; M = Mm; KT = KTm; Kpad = padKm;
      rowBlk = b2 % rbM; split = b2 / rbM;
    }
  }
  const int rowBase = rowBlk * 128;
  const int NS = Kpad >> 5;
  const int s0 = split * 64;
  const int ns = min(64, NS - s0);

  f32x4 acc[2][4];
  #pragma unroll
  for (int m = 0; m < 2; ++m)
    #pragma unroll
    for (int n = 0; n < 4; ++n)
      acc[m][n] = (f32x4){0.f, 0.f, 0.f, 0.f};

  const __bf16* aBase = Ac + (((size_t)rowBlk * KT) << 13)
                      + (size_t)(w * 2) * 512 + (size_t)lane * 8;
  const __bf16* bSrc = BT + (size_t)(w * 16 + (lane >> 2)) * Kpad
                     + (size_t)(((lane & 3) ^ ((lane >> 3) & 3)) * 8);

  auto stage = [&](int buf, int h) {
    const size_t ko = ((size_t)(s0 + h)) << 12;   // half-tile offset (elems)
    gload16(aBase + ko,       &sA[buf][(w * 2 + 0) * 512]);
    gload16(aBase + ko + 512, &sA[buf][(w * 2 + 1) * 512]);
    gload16(bSrc + (s0 + h) * 32, &sB[buf][w * 512]);
  };

  auto cons = [&](int buf) {
    FragU aF[2], bF[4];
    aF[0].s = *(const short8*)&sA[buf][(w * 2 + 0) * 512 + lane * 8];
    aF[1].s = *(const short8*)&sA[buf][(w * 2 + 1) * 512 + lane * 8];
    const int gb = g ^ ((r >> 1) & 3);
    #pragma unroll
    for (int n = 0; n < 4; ++n)
      bF[n].s = *(const short8*)&sB[buf][(n * 16 + r) * 32 + gb * 8];
    #pragma unroll
    for (int m = 0; m < 2; ++m)
      #pragma unroll
      for (int n = 0; n < 4; ++n)
        acc[m][n] = __builtin_amdgcn_mfma_f32_16x16x32_bf16(
            aF[m].s, bF[n].s, acc[m][n], 0, 0, 0);
  };

  stage(0, 0); stage(1, 1);

  for (int h = 0; h < ns; ++h) {
    asm volatile("s_waitcnt vmcnt(3)" ::: "memory");  // tile h landed
    __builtin_amdgcn_s_barrier();
    asm volatile("" ::: "memory");
    cons(h % 3);
    int hs = h + 2; if (hs > ns - 1) hs = ns - 1;     // clamp keeps queue full
    stage((h + 2) % 3, hs);
  }

  float* Pp = P + (size_t)split * M * 64;
  #pragma unroll
  for (int m = 0; m < 2; ++m) {
    #pragma unroll
    for (int j = 0; j < 4; ++j) {
      const int row = rowBase + w * 32 + m * 16 + g * 4 + j;
      if (row < M) {
        #pragma unroll
        for (int n = 0; n < 4; ++n)
          Pp[(size_t)row * 64 + n * 16 + r] = acc[m][n][j];
      }
    }
  }
}

// ---------------------------------------------------------------------------
// Transpose + f32->bf16 convert with K padding (layer-0 embeddings only):
//   in[K][64] f32 -> out[64][Kpad] bf16 (pad region zero-filled)
// ---------------------------------------------------------------------------
__global__ __launch_bounds__(256) void transpose_cvt(
    const float* __restrict__ in, __bf16* __restrict__ out, int K, int Kpad)
{
  __shared__ float tile[64][65];
  const int t = threadIdx.x;
  const int k0 = blockIdx.x * 64;
  #pragma unroll
  for (int i = 0; i < 4; ++i) {
    int f = t + i * 256;
    int k = f >> 4;
    int cc = (f & 15) << 2;
    if (k0 + k < K) {
      f32x4 v = *(const f32x4*)(in + (size_t)(k0 + k) * 64 + cc);
      tile[k][cc + 0] = v[0]; tile[k][cc + 1] = v[1];
      tile[k][cc + 2] = v[2]; tile[k][cc + 3] = v[3];
    }
  }
  __syncthreads();
  const int c = t >> 2;
  const int kc = (t & 3) << 4;
  #pragma unroll
  for (int h = 0; h < 2; ++h) {
    int kk = kc + h * 8;
    FragU p;
    if (k0 + kk < K) {
      #pragma unroll
      for (int j = 0; j < 8; ++j) p.h[j] = (__bf16)tile[kk + j][c];
    } else {
      p.s = (short8){0,0,0,0,0,0,0,0};
    }
    *(short8*)(out + (size_t)c * Kpad + k0 + kk) = p.s;
  }
}

// ---------------------------------------------------------------------------
// out[i][c] = LeakyReLU( (sum_s P[s][i][:] + self[i][:]) . W[c][:] + 2*b[c] )
// Also (if Kpad>0) writes the bf16 transpose outT[c][i] for the next layer's B.
// (outT pad region [M..Kpad) stays zero from the layer-0 transpose_cvt fill.)
// ---------------------------------------------------------------------------
__global__ __launch_bounds__(256) void layer_reduce(
    const float* __restrict__ P, int S,
    const float* __restrict__ self, const float* __restrict__ W,
    const float* __restrict__ b, float* __restrict__ out,
    __bf16* __restrict__ outT, int Kpad, int M)
{
  __shared__ float xs[4][64];
  const int t = threadIdx.x;
  const int c = t & 63;
  const int grp = t >> 6;
  const int row = blockIdx.x * 4 + grp;
  if (row < M) {
    float x = self[(size_t)row * 64 + c];
    for (int s = 0; s < S; ++s)
      x += P[(size_t)s * M * 64 + (size_t)row * 64 + c];
    xs[grp][c] = x;
  }
  __syncthreads();
  if (row >= M) return;
  float acc = 0.f;
  const f32x4* Wc = (const f32x4*)(W + c * 64);
  #pragma unroll
  for (int k4 = 0; k4 < 16; ++k4) {
    f32x4 wv = Wc[k4];
    acc += xs[grp][k4 * 4 + 0] * wv[0] + xs[grp][k4 * 4 + 1] * wv[1]
         + xs[grp][k4 * 4 + 2] * wv[2] + xs[grp][k4 * 4 + 3] * wv[3];
  }
  float v = acc + 2.0f * b[c];
  v = (v > 0.f) ? v : 0.01f * v;
  out[(size_t)row * 64 + c] = v;
  if (Kpad > 0) outT[(size_t)c * Kpad + row] = (__bf16)v;
}

// ---------------------------------------------------------------------------
__global__ __launch_bounds__(256) void gather_score(
    const int* __restrict__ uid, const int* __restrict__ mid,
    const float* __restrict__ u0, const float* __restrict__ u1,
    const float* __restrict__ u2, const float* __restrict__ u3,
    const float* __restrict__ m0, const float* __restrict__ m1,
    const float* __restrict__ m2, const float* __restrict__ m3,
    const float* __restrict__ oW, const float* __restrict__ ob,
    float* __restrict__ scores, int B)
{
  const int wave = threadIdx.x >> 6;
  const int lane = threadIdx.x & 63;
  const int b = blockIdx.x * 4 + wave;
  if (b >= B) return;
  const size_t ub = (size_t)uid[b] * 64 + lane;
  const size_t mb = (size_t)mid[b] * 64 + lane;
  float acc = u0[ub] * m0[mb] * oW[lane]
            + u1[ub] * m1[mb] * oW[64 + lane]
            + u2[ub] * m2[mb] * oW[128 + lane]
            + u3[ub] * m3[mb] * oW[192 + lane];
  #pragma unroll
  for (int off = 32; off > 0; off >>= 1)
    acc += __shfl_down(acc, off, 64);
  if (lane == 0) scores[b] = acc + ob[0];
}

// ---------------------------------------------------------------------------
extern "C" void kernel_launch(void* const* d_in, const int* in_sizes, int n_in,
                              void* d_out, int out_size, void* d_ws, size_t ws_size,
                              hipStream_t stream)
{
  const float* user_adj  = (const float*)d_in[0];
  const float* movie_adj = (const float*)d_in[1];
  const int*   user_id   = (const int*)d_in[2];
  const int*   movie_id  = (const int*)d_in[3];
  const float* user_emb  = (const float*)d_in[4];
  const float* movie_emb = (const float*)d_in[5];
  const float* user_Ws   = (const float*)d_in[6];
  const float* user_bs   = (const float*)d_in[7];
  const float* movie_Ws  = (const float*)d_in[8];
  const float* movie_bs  = (const float*)d_in[9];
  const float* out_W     = (const float*)d_in[10];
  const float* out_b     = (const float*)d_in[11];

  const int NU = 20000, NM = 10000, E = 64, B = 8192;
  const int rbU = 157, rbM = 79;          // ceil(M/128)
  const int KT_U = 157, KT_M = 313;       // ceil(K/64)
  const int NMpad = KT_U * 64;            // 10048
  const int NUpad = KT_M * 64;            // 20032
  const int SU = 5, SM = 10;              // k-splits (32 x 64-k tiles each)

  char* ws = (char*)d_ws;
  size_t o = 0;
  __bf16* Au_c = (__bf16*)(ws + o); o += (size_t)rbU * KT_U * 16384;  // 403.8 MB
  __bf16* Am_c = (__bf16*)(ws + o); o += (size_t)rbM * KT_M * 16384;  // 405.1 MB
  float*  uP   = (float*)(ws + o);  o += (size_t)SU * NU * 64 * 4;
  float*  mP   = (float*)(ws + o);  o += (size_t)SM * NM * 64 * 4;
  float*  u1   = (float*)(ws + o);  o += (size_t)NU * 64 * 4;
  float*  u2   = (float*)(ws + o);  o += (size_t)NU * 64 * 4;
  float*  m1   = (float*)(ws + o);  o += (size_t)NM * 64 * 4;
  float*  m2   = (float*)(ws + o);  o += (size_t)NM * 64 * 4;
  __bf16* uT   = (__bf16*)(ws + o); o += (size_t)64 * NUpad * 2;
  __bf16* mT   = (__bf16*)(ws + o); o += (size_t)64 * NMpad * 2;

  float* scores = (float*)d_out;
  float* u3 = scores + B;
  float* m3 = u3 + (size_t)NU * E;

  const int nbU = rbU * SU;   // 785
  const int nbM = rbM * SM;   // 790

  // layer 0: B = embeddings (transpose_cvt also zero-fills the pad region,
  // which subsequent fused layer_reduce transposed-writes never touch)
  transpose_cvt<<<NMpad / 64, 256, 0, stream>>>(movie_emb, mT, NM, NMpad);
  transpose_cvt<<<NUpad / 64, 256, 0, stream>>>(user_emb, uT, NU, NUpad);

  gemm_l0<<<nbU + nbM, 256, 0, stream>>>(
      user_adj, mT, Au_c, uP, NU, NM, KT_U, NMpad,
      movie_adj, uT, Am_c, mP, NM, NU, KT_M, NUpad,
      nbU, rbU, rbM);

  layer_reduce<<<(NU + 3) / 4, 256, 0, stream>>>(
      uP, SU, user_emb, user_Ws, user_bs, u1, uT, NUpad, NU);
  layer_reduce<<<(NM + 3) / 4, 256, 0, stream>>>(
      mP, SM, movie_emb, movie_Ws, movie_bs, m1, mT, NMpad, NM);

  const float* uCur = u1;
  const float* mCur = m1;
  for (int l = 1; l < 3; ++l) {
    float* uNext = (l == 1) ? u2 : u3;
    float* mNext = (l == 1) ? m2 : m3;
    const int wT = (l == 1) ? 1 : 0;   // layer 2 output needs no transpose

    gemm_l12<<<nbU + nbM, 256, 0, stream>>>(
        Au_c, mT, uP, NU, KT_U, NMpad,
        Am_c, uT, mP, NM, KT_M, NUpad,
        nbU, rbU, rbM);

    layer_reduce<<<(NU + 3) / 4, 256, 0, stream>>>(
        uP, SU, uCur, user_Ws + (size_t)l * E * E, user_bs + (size_t)l * E,
        uNext, uT, wT ? NUpad : 0, NU);
    layer_reduce<<<(NM + 3) / 4, 256, 0, stream>>>(
        mP, SM, mCur, movie_Ws + (size_t)l * E * E, movie_bs + (size_t)l * E,
        mNext, mT, wT ? NMpad : 0, NM);
    uCur = uNext; mCur = mNext;
  }
  gather_score<<<(B + 3) / 4, 256, 0, stream>>>(
      user_id, movie_id, user_emb, u1, u2, u3,
      movie_emb, m1, m2, m3, out_W, out_b, scores, B);
}